// Round 1
// baseline (54.985 us; speedup 1.0000x reference)
//
#include <hip/hip_runtime.h>

// QLayer analytic collapse:
//   state before CNOTs is a product state; per-qubit <Z> = cos^2(x).
//   CNOT chain maps Z_w -> Z_0 Z_1 ... Z_w, so
//   out[b,w] = prod_{k<=w} cos^2(x[b,k]).   (params drop out: RZ is diagonal.)
// One thread per batch row; float4 vectorized row load/store.

#define N_QUBITS 16

__global__ __launch_bounds__(256) void qlayer_prefix_kernel(
    const float* __restrict__ x, float* __restrict__ out, int B) {
    int b = blockIdx.x * blockDim.x + threadIdx.x;
    if (b >= B) return;

    const float4* __restrict__ xin = (const float4*)(x + (size_t)b * N_QUBITS);
    float4 v0 = xin[0];
    float4 v1 = xin[1];
    float4 v2 = xin[2];
    float4 v3 = xin[3];

    float a[N_QUBITS] = {v0.x, v0.y, v0.z, v0.w,
                         v1.x, v1.y, v1.z, v1.w,
                         v2.x, v2.y, v2.z, v2.w,
                         v3.x, v3.y, v3.z, v3.w};

    float o[N_QUBITS];
    float p = 1.0f;
#pragma unroll
    for (int w = 0; w < N_QUBITS; ++w) {
        float c = cosf(a[w]);
        p *= c * c;
        o[w] = p;
    }

    float4* __restrict__ op = (float4*)(out + (size_t)b * N_QUBITS);
    op[0] = make_float4(o[0],  o[1],  o[2],  o[3]);
    op[1] = make_float4(o[4],  o[5],  o[6],  o[7]);
    op[2] = make_float4(o[8],  o[9],  o[10], o[11]);
    op[3] = make_float4(o[12], o[13], o[14], o[15]);
}

extern "C" void kernel_launch(void* const* d_in, const int* in_sizes, int n_in,
                              void* d_out, int out_size, void* d_ws, size_t ws_size,
                              hipStream_t stream) {
    const float* x = (const float*)d_in[0];
    // d_in[1] (params) provably does not affect the output.
    float* out = (float*)d_out;
    int B = in_sizes[0] / N_QUBITS;  // 512

    int block = 256;
    int grid = (B + block - 1) / block;  // 2
    qlayer_prefix_kernel<<<grid, block, 0, stream>>>(x, out, B);
}